// Round 14
// baseline (273.423 us; speedup 1.0000x reference)
//
#include <hip/hip_runtime.h>
#include <math.h>

// PGTAttention fused block, MI355X gfx950. Round 14.
// Change vs r12/r13: attention re-split by q (not KV): 512 blocks x 256 thr (4 waves),
// block = one (bh, qt) q-tile over its FULL causal KV range -> online softmax finishes
// in-block, NO merge kernel / global partials (r13's 17us tax). 52KB LDS -> 2 blocks/CU:
// two independent barrier groups per CU fill each other's stalls (r9/m114 mechanism,
// unavailable to r12's 8 lockstep waves). Block order: qt 0..15 first 256, 31..16
// second 256 -> round-robin slot filling pairs light+heavy (68 tiles/CU uniform).
// GEMMs / prep / tv / buffers frozen from r12.

typedef unsigned short u16;
typedef unsigned int   u32;
typedef u16   u16x8 __attribute__((ext_vector_type(8)));
typedef __bf16 bf16x8 __attribute__((ext_vector_type(8)));
typedef float f32x4 __attribute__((ext_vector_type(4)));

#define GPTR(p) ((const __attribute__((address_space(1))) void*)(p))
#define LPTR(p) ((__attribute__((address_space(3))) void*)(p))

__device__ __forceinline__ u16 f2bf(float x) {
  u32 u = __float_as_uint(x);
  return (u16)((u + 0x7fffu + ((u >> 16) & 1u)) >> 16);  // RNE
}

__device__ __forceinline__ bf16x8 ld8(const void* p) {
  u16x8 v = *reinterpret_cast<const u16x8*>(p);
  return __builtin_bit_cast(bf16x8, v);
}

// global->LDS direct copy, 16B/lane; LDS dest = wave-uniform base + lane*16.
__device__ __forceinline__ void g2l16(const void* g, void* l) {
  __builtin_amdgcn_global_load_lds(GPTR(g), LPTR(l), 16, 0, 0);
}

// ---------------- fused prep: cast hs->Xb | tcast wat->Wa_t | tcast wpr->Wp_t --------
__global__ void prep_kernel(const float* __restrict__ hs, const float* __restrict__ wat,
                            const float* __restrict__ wpr, u16* __restrict__ Xb,
                            u16* __restrict__ Wa_t, u16* __restrict__ Wp_t) {
  __shared__ float t[32][33];
  const int bid = blockIdx.x, tid = threadIdx.x;
  if (bid < 4096) {
    int i = bid * 256 + tid;
    const float4* p = reinterpret_cast<const float4*>(hs) + (size_t)i * 2;
    float4 a = p[0], b = p[1];
    u16x8 v;
    v[0] = f2bf(a.x); v[1] = f2bf(a.y); v[2] = f2bf(a.z); v[3] = f2bf(a.w);
    v[4] = f2bf(b.x); v[5] = f2bf(b.y); v[6] = f2bf(b.z); v[7] = f2bf(b.w);
    reinterpret_cast<u16x8*>(Xb)[i] = v;
    return;
  }
  const float* in; u16* out; int R, C, bx, by;
  if (bid < 16384) {
    int b2 = bid - 4096;
    in = wat; out = Wa_t; R = 2048; C = 6144;
    bx = (b2 % 192) * 32; by = (b2 / 192) * 32;
  } else {
    int b3 = bid - 16384;
    in = wpr; out = Wp_t; R = 2048; C = 2048;
    bx = (b3 % 64) * 32; by = (b3 / 64) * 32;
  }
  int x = tid & 31, y = tid >> 5;  // (32, 8)
  #pragma unroll
  for (int k = 0; k < 32; k += 8)
    t[y + k][x] = in[(size_t)(by + y + k) * C + (bx + x)];
  __syncthreads();
  #pragma unroll
  for (int k = 0; k < 32; k += 8)
    out[(size_t)(bx + y + k) * R + (by + x)] = f2bf(t[x][y + k]);
}

// ------- V transpose from qkv: out[bh][d][s] = qkv[b][s][4096 + h*256 + d] ----------
__global__ void tv_kernel(const u16* __restrict__ qkv, u16* __restrict__ out) {
  __shared__ u16 t[32][33];
  int bh = blockIdx.z, b = bh >> 3, h = bh & 7;
  const u16* ip = qkv + (size_t)b * 2048 * 6144 + 4096 + h * 256;
  u16* op = out + (size_t)bh * 256 * 2048;
  int bx = blockIdx.x * 32, by = blockIdx.y * 32;  // bx: d, by: s
  int x = threadIdx.x, y = threadIdx.y;
  #pragma unroll
  for (int k = 0; k < 32; k += 8)
    t[y + k][x] = ip[(size_t)(by + y + k) * 6144 + (bx + x)];
  __syncthreads();
  #pragma unroll
  for (int k = 0; k < 32; k += 8)
    op[(size_t)(bx + y + k) * 2048 + (by + x)] = t[x][y + k];
}

// ------------- 2-blocks/CU pipelined GEMM: C = A[M,K] * Bt[N,K]^T (bf16 in) -------------
// Unchanged from r12 (measured 1033 TF, MfmaUtil 48%, 0 conflicts).
template<int WM, int WN, int MF, int NF, bool F32OUT>
__global__ __launch_bounds__(512, 4) void gemm2b_kernel(
    const u16* __restrict__ A, const u16* __restrict__ Bt,
    float* __restrict__ Cf, u16* __restrict__ Cb, int M, int N, int K) {
  constexpr int BM = WM * MF * 16;
  constexpr int BN = WN * NF * 16;
  constexpr int TILEB = (BM + BN) * 128;
  constexpr int NSTG = TILEB / 8192;
  __shared__ __align__(16) char smem[2 * TILEB];

  const int tid = threadIdx.x, lane = tid & 63, w = tid >> 6;
  const int wr = w / WN, wc = w % WN;
  const int g = lane >> 4, li = lane & 15;
  const int bn = blockIdx.x * BN, bm = blockIdx.y * BM;

  const char* src[NSTG]; u32 dOff[NSTG];
  #pragma unroll
  for (int j = 0; j < NSTG; ++j) {
    int o = j * 8192 + tid * 16;
    if (o < BM * 128) {
      int row = o >> 7;
      int col = (o & 127) ^ ((row & 7) << 4);
      src[j] = (const char*)A + (size_t)(bm + row) * K * 2 + col;
    } else {
      int rem = o - BM * 128;
      int row = rem >> 7;
      int col = (rem & 127) ^ ((row & 7) << 4);
      src[j] = (const char*)Bt + (size_t)(bn + row) * K * 2 + col;
    }
    dOff[j] = (u32)(o - lane * 16);
  }

  u32 aRd[2][MF], bRd[2][NF];
  #pragma unroll
  for (int ks = 0; ks < 2; ++ks) {
    #pragma unroll
    for (int mf = 0; mf < MF; ++mf) {
      int row = wr * (MF * 16) + mf * 16 + li;
      aRd[ks][mf] = row * 128 + ((ks * 64 + g * 16) ^ ((row & 7) << 4));
    }
    #pragma unroll
    for (int nf = 0; nf < NF; ++nf) {
      int row = wc * (NF * 16) + nf * 16 + li;
      bRd[ks][nf] = BM * 128 + row * 128 + ((ks * 64 + g * 16) ^ ((row & 7) << 4));
    }
  }

  const f32x4 fz = {0.f, 0.f, 0.f, 0.f};
  f32x4 acc[MF][NF];
  #pragma unroll
  for (int i = 0; i < MF; ++i)
    #pragma unroll
    for (int j = 0; j < NF; ++j) acc[i][j] = fz;

  const int NT = K >> 6;
  #pragma unroll
  for (int j = 0; j < NSTG; ++j) { g2l16(src[j], smem + dOff[j]); src[j] += 128; }

  for (int t = 0; t < NT; ++t) {
    const int cur = t & 1;
    const bool more = (t + 1 < NT);
    asm volatile("s_barrier" ::: "memory");
    if (more) {
      char* nb = smem + (cur ^ 1) * TILEB;
      #pragma unroll
      for (int j = 0; j < NSTG; ++j) { g2l16(src[j], nb + dOff[j]); src[j] += 128; }
      asm volatile("s_waitcnt vmcnt(%0)" :: "i"(NSTG) : "memory");
    } else {
      asm volatile("s_waitcnt vmcnt(0)" ::: "memory");
    }
    asm volatile("s_barrier" ::: "memory");

    const char* sb = smem + cur * TILEB;
    #pragma unroll
    for (int ks = 0; ks < 2; ++ks) {
      bf16x8 aR[MF], bR[NF];
      #pragma unroll
      for (int mf = 0; mf < MF; ++mf) aR[mf] = ld8(sb + aRd[ks][mf]);
      #pragma unroll
      for (int nf = 0; nf < NF; ++nf) bR[nf] = ld8(sb + bRd[ks][nf]);
      __builtin_amdgcn_s_setprio(1);
      #pragma unroll
      for (int mf = 0; mf < MF; ++mf)
        #pragma unroll
        for (int nf = 0; nf < NF; ++nf)
          acc[mf][nf] = __builtin_amdgcn_mfma_f32_16x16x32_bf16(aR[mf], bR[nf], acc[mf][nf], 0, 0, 0);
      __builtin_amdgcn_s_setprio(0);
    }
  }

  #pragma unroll
  for (int mf = 0; mf < MF; ++mf)
    #pragma unroll
    for (int nf = 0; nf < NF; ++nf)
      #pragma unroll
      for (int r = 0; r < 4; ++r) {
        int gm = bm + wr * (MF * 16) + mf * 16 + g * 4 + r;
        int gn = bn + wc * (NF * 16) + nf * 16 + li;
        if (F32OUT) Cf[(size_t)gm * N + gn] = acc[mf][nf][r];
        else        Cb[(size_t)gm * N + gn] = f2bf(acc[mf][nf][r]);
      }
}

// ---------------- flash attention + fused PMSNorm: one q-tile per block ----------------
// 512 blocks x 256 thr (4 waves, 16 q-rows each), 2 blocks/CU (52 KB LDS).
// Block c: bh=c&15, iu=(c>>4)&15; qt = (c<256) ? iu : 31-iu  -> first dispatch round
// gets light blocks, second gets heavy; co-resident pair sums to 68 tiles (uniform).
// Full causal KV range per block (nt = 2qt+2 tiles of 32) -> softmax completes
// in-block, direct PMSNorm epilogue (no merge). Inner loop = r12-verified body.
__global__ __launch_bounds__(256, 2) void attn_kernel(
    const u16* __restrict__ qkv, const u16* __restrict__ Vt,
    const float* __restrict__ nw, u16* __restrict__ Mrg) {
  __shared__ __align__(16) u16 sK[2][32 * 256];   // 32 KiB
  __shared__ __align__(16) u16 sV[256 * 32];      // 16 KiB
  __shared__ __align__(16) u16 sP[4 * 16 * 32];   //  4 KiB

  const int c = blockIdx.x;
  const int bh = c & 15, iu = (c >> 4) & 15;
  const int qt = (c < 256) ? iu : 31 - iu;
  const int b = bh >> 3, h = bh & 7;
  const int tid = threadIdx.x, lane = tid & 63, wq = tid >> 6;
  const int g = lane >> 4, li = lane & 15;
  const float MASKV = -30000.0f;
  const float MINIT = -1000.0f;
  const float isc = 1.0f / 64.0f;  // 1 / (sqrt(256) * (LAYER_IDX+1))
  const f32x4 fz = {0.f, 0.f, 0.f, 0.f};
  const size_t KADV = (size_t)32 * 6144 * 2;

  const int nt = 2 * qt + 2;  // KV tiles of 32 (covers cols 0 .. 64*qt+63)

  // Q fragments (16 rows/wave)
  int qrow = qt * 64 + wq * 16 + li;
  const u16* qp = qkv + (size_t)(b * 2048 + qrow) * 6144 + h * 256;
  bf16x8 qf[8];
  #pragma unroll
  for (int c8 = 0; c8 < 8; ++c8) qf[c8] = ld8(qp + c8 * 32 + g * 8);

  // K staging: tile [32][256] = 16 chunks of 1KB, 4/wave; rows 512B, swz (row&7)<<4
  const char* kSrc[4]; u32 kDoff[4];
  #pragma unroll
  for (int j = 0; j < 4; ++j) {
    int chunk = wq * 4 + j;
    int o = chunk * 1024 + lane * 16;
    int row = o >> 9, cb = o & 511;
    int cbs = cb ^ ((row & 7) << 4);
    kSrc[j] = (const char*)qkv + ((size_t)(b * 2048 + row) * 6144 + 2048 + h * 256) * 2 + cbs;
    kDoff[j] = chunk * 1024;
  }
  // V staging: tile [256 d][32 s], rows 64B, swz ((row>>1)&3)<<4
  const char* vSrc[4]; char* vDst[4];
  #pragma unroll
  for (int j = 0; j < 4; ++j) {
    int chunk = wq * 4 + j;
    int o = chunk * 1024 + lane * 16;
    int row = o >> 6, cb = o & 63;
    int cbs = cb ^ (((row >> 1) & 3) << 4);
    vSrc[j] = (const char*)Vt + ((size_t)(bh * 256 + row) * 2048) * 2 + cbs;
    vDst[j] = (char*)sV + chunk * 1024;
  }

  f32x4 o_[16];
  #pragma unroll
  for (int nf = 0; nf < 16; ++nf) o_[nf] = fz;
  float m_[4] = {MINIT, MINIT, MINIT, MINIT};
  float l_[4] = {0.f, 0.f, 0.f, 0.f};  // lane-partial

  // prologue: stage K(0) into buf 0
  #pragma unroll
  for (int j = 0; j < 4; ++j) { g2l16(kSrc[j], (char*)sK[0] + kDoff[j]); kSrc[j] += KADV; }
  asm volatile("s_waitcnt vmcnt(0)" ::: "memory");
  asm volatile("s_barrier" ::: "memory");

  int cur = 0;
  for (int t = 0; t < nt; ++t) {
    const bool more = (t < nt - 1);
    #pragma unroll
    for (int j = 0; j < 4; ++j) { g2l16(vSrc[j], vDst[j]); vSrc[j] += 64; }
    if (more) {
      char* kb = (char*)sK[cur ^ 1];
      #pragma unroll
      for (int j = 0; j < 4; ++j) { g2l16(kSrc[j], kb + kDoff[j]); kSrc[j] += KADV; }
    }

    // S = Q * K^T
    f32x4 sacc[2];
    const char* kbase = (const char*)sK[cur];
    __builtin_amdgcn_s_setprio(1);
    #pragma unroll
    for (int nf = 0; nf < 2; ++nf) {
      int row = nf * 16 + li;
      int swz = (row & 7) << 4;
      const char* kr = kbase + row * 512;
      f32x4 sa = fz, sb = fz;
      #pragma unroll
      for (int c8 = 0; c8 < 4; ++c8) {
        sa = __builtin_amdgcn_mfma_f32_16x16x32_bf16(qf[c8],     ld8(kr + ((c8 * 64 + g * 16) ^ swz)),       sa, 0, 0, 0);
        sb = __builtin_amdgcn_mfma_f32_16x16x32_bf16(qf[c8 + 4], ld8(kr + (((c8 + 4) * 64 + g * 16) ^ swz)), sb, 0, 0, 0);
      }
      sacc[nf] = sa + sb;
    }
    __builtin_amdgcn_s_setprio(0);

    // lazy softmax
    const bool diag = (t >= 2 * qt);
    float p[2][4], m0[4];
    #pragma unroll
    for (int r = 0; r < 4; ++r) {
      int qr = qt * 64 + wq * 16 + g * 4 + r;
      float a0 = sacc[0][r] * isc;
      float a1 = sacc[1][r] * isc;
      if (diag) {
        if (t * 32 + li > qr) a0 = MASKV;
        if (t * 32 + 16 + li > qr) a1 = MASKV;
      }
      p[0][r] = a0; p[1][r] = a1;
      m0[r] = fmaxf(a0, a1);
    }
    bool need = (m0[0] > m_[0] + 8.f) || (m0[1] > m_[1] + 8.f) ||
                (m0[2] > m_[2] + 8.f) || (m0[3] > m_[3] + 8.f);
    if (__any(need)) {
      #pragma unroll
      for (int r = 0; r < 4; ++r) {
        float mx = m0[r];
        mx = fmaxf(mx, __shfl_xor(mx, 1));
        mx = fmaxf(mx, __shfl_xor(mx, 2));
        mx = fmaxf(mx, __shfl_xor(mx, 4));
        mx = fmaxf(mx, __shfl_xor(mx, 8));
        float mn = fmaxf(m_[r], mx);
        float sc = __expf(m_[r] - mn);
        l_[r] *= sc; m_[r] = mn;
        #pragma unroll
        for (int nf = 0; nf < 16; ++nf) o_[nf][r] *= sc;
      }
    }
    #pragma unroll
    for (int r = 0; r < 4; ++r) {
      float e0 = __expf(p[0][r] - m_[r]);
      float e1 = __expf(p[1][r] - m_[r]);
      p[0][r] = e0; p[1][r] = e1;
      l_[r] += e0 + e1;
    }

    if (more) asm volatile("s_waitcnt vmcnt(4)" ::: "memory");
    else      asm volatile("s_waitcnt vmcnt(0)" ::: "memory");
    asm volatile("s_barrier" ::: "memory");

    // P -> per-wave swizzled LDS
    char* sPw = (char*)sP + wq * 1024;
    #pragma unroll
    for (int r = 0; r < 4; ++r) {
      int row = g * 4 + r;
      int swz = ((row >> 1) & 3) << 4;
      #pragma unroll
      for (int nf = 0; nf < 2; ++nf)
        *(u16*)(sPw + row * 64 + (((nf * 16 + li) * 2) ^ swz)) = f2bf(p[nf][r]);
    }
    asm volatile("s_waitcnt lgkmcnt(0)" ::: "memory");
    __builtin_amdgcn_sched_barrier(0);

    // O += P * V
    __builtin_amdgcn_s_setprio(1);
    {
      bf16x8 pa = ld8(sPw + li * 64 + ((g * 16) ^ (((li >> 1) & 3) << 4)));
      #pragma unroll
      for (int nf = 0; nf < 16; ++nf) {
        int row = nf * 16 + li;
        bf16x8 vf = ld8((const char*)sV + row * 64 + ((g * 16) ^ (((row >> 1) & 3) << 4)));
        o_[nf] = __builtin_amdgcn_mfma_f32_16x16x32_bf16(pa, vf, o_[nf], 0, 0, 0);
      }
    }
    __builtin_amdgcn_s_setprio(0);

    asm volatile("s_barrier" ::: "memory");  // sV free for next tile
    if (more) asm volatile("s_waitcnt vmcnt(0)" ::: "memory");  // K(t+1) landed
    cur ^= 1;
  }

  // epilogue: reduce lane-partial l, 1/l, PMSNorm over d=256, *nw, write Mrg bf16
  #pragma unroll
  for (int r = 0; r < 4; ++r) {
    float ls = l_[r];
    ls += __shfl_xor(ls, 1);
    ls += __shfl_xor(ls, 2);
    ls += __shfl_xor(ls, 4);
    ls += __shfl_xor(ls, 8);
    float inv_l = 1.0f / ls;
    float ss = 0.f;
    #pragma unroll
    for (int nf = 0; nf < 16; ++nf) {
      float v = o_[nf][r] * inv_l;
      ss += v * v;
    }
    ss += __shfl_xor(ss, 1);
    ss += __shfl_xor(ss, 2);
    ss += __shfl_xor(ss, 4);
    ss += __shfl_xor(ss, 8);
    float rms = rsqrtf(ss * (1.0f / 256.0f) + 1e-5f);
    int row = qt * 64 + wq * 16 + g * 4 + r;
    #pragma unroll
    for (int nf = 0; nf < 16; ++nf) {
      int d = nf * 16 + li;
      float v = o_[nf][r] * inv_l * rms * nw[d];
      Mrg[((size_t)(b * 2048 + row)) * 2048 + h * 256 + d] = f2bf(v);
    }
  }
}

extern "C" void kernel_launch(void* const* d_in, const int* in_sizes, int n_in,
                              void* d_out, int out_size, void* d_ws, size_t ws_size,
                              hipStream_t stream) {
  const float* hs  = (const float*)d_in[0];   // [2,2048,2048]
  const float* wat = (const float*)d_in[1];   // [2048,6144]
  const float* wpr = (const float*)d_in[2];   // [2048,2048]
  const float* nw  = (const float*)d_in[3];   // [256]
  float* out = (float*)d_out;                 // [2,2048,2048] f32

  char* ws = (char*)d_ws;
  u16* Xb   = (u16*)(ws + 0);                    // 16 MiB  [4096][2048] bf16
  u16* Wp_t = (u16*)(ws + (16u << 20));          //  8 MiB  [2048][2048] bf16 (w_proj^T)
  u16* Qkv  = (u16*)(ws + (24u << 20));          // 48 MiB  [4096][6144] bf16
  u16* Vt   = (u16*)(ws + (72u << 20));          // 16 MiB  [16][256][2048] bf16
  u16* Mrg  = Xb;                                // aliases Xb (dead after GEMM1)
  u16* Wa_t = (u16*)d_out;                       // 24 MiB scratch (w_attn^T [6144][2048])

  dim3 t328(32, 8);
  prep_kernel<<<20480, 256, 0, stream>>>(hs, wat, wpr, Xb, Wa_t, Wp_t);
  // qkv: 128x192 tile -> grid 32x32 = 1024 blocks = 2 exact rounds at 2 blocks/CU
  gemm2b_kernel<2, 4, 4, 3, false><<<dim3(32, 32), 512, 0, stream>>>(
      Xb, Wa_t, nullptr, Qkv, 4096, 6144, 2048);
  tv_kernel<<<dim3(8, 64, 16), t328, 0, stream>>>(Qkv, Vt);
  attn_kernel<<<512, 256, 0, stream>>>(Qkv, Vt, nw, Mrg);
  // proj: 128x128 tile -> grid 16x32 = 512 blocks = 1 exact round at 2 blocks/CU
  gemm2b_kernel<2, 4, 4, 2, true><<<dim3(16, 32), 512, 0, stream>>>(
      Mrg, Wp_t, out, nullptr, 4096, 2048, 2048);
  (void)in_sizes; (void)n_in; (void)out_size; (void)ws_size;
}

// Round 15
// 232.863 us; speedup vs baseline: 1.1742x; 1.1742x over previous
//
#include <hip/hip_runtime.h>
#include <math.h>

// PGTAttention fused block, MI355X gfx950. Round 15 = r12 (measured best, 233.4 us).
// r13 (global-merge split) and r14 (q-split blocks) both hit their failure
// signatures; r12's in-block split-k attention is the verified load-balance +
// occupancy sweet spot. Pipeline: fused prep -> gemm2b qkv (128x192, 2 blk/CU,
// counted vmcnt, 1033 TF) -> tv -> attn (8-wave in-block split-k, lazy softmax,
// fused PMSNorm) -> gemm2b proj (128x128, f32 out).

typedef unsigned short u16;
typedef unsigned int   u32;
typedef u16   u16x8 __attribute__((ext_vector_type(8)));
typedef __bf16 bf16x8 __attribute__((ext_vector_type(8)));
typedef float f32x4 __attribute__((ext_vector_type(4)));

#define GPTR(p) ((const __attribute__((address_space(1))) void*)(p))
#define LPTR(p) ((__attribute__((address_space(3))) void*)(p))

__device__ __forceinline__ u16 f2bf(float x) {
  u32 u = __float_as_uint(x);
  return (u16)((u + 0x7fffu + ((u >> 16) & 1u)) >> 16);  // RNE
}

__device__ __forceinline__ bf16x8 ld8(const void* p) {
  u16x8 v = *reinterpret_cast<const u16x8*>(p);
  return __builtin_bit_cast(bf16x8, v);
}

// global->LDS direct copy, 16B/lane; LDS dest = wave-uniform base + lane*16.
__device__ __forceinline__ void g2l16(const void* g, void* l) {
  __builtin_amdgcn_global_load_lds(GPTR(g), LPTR(l), 16, 0, 0);
}

// ---------------- fused prep: cast hs->Xb | tcast wat->Wa_t | tcast wpr->Wp_t --------
__global__ void prep_kernel(const float* __restrict__ hs, const float* __restrict__ wat,
                            const float* __restrict__ wpr, u16* __restrict__ Xb,
                            u16* __restrict__ Wa_t, u16* __restrict__ Wp_t) {
  __shared__ float t[32][33];
  const int bid = blockIdx.x, tid = threadIdx.x;
  if (bid < 4096) {
    int i = bid * 256 + tid;
    const float4* p = reinterpret_cast<const float4*>(hs) + (size_t)i * 2;
    float4 a = p[0], b = p[1];
    u16x8 v;
    v[0] = f2bf(a.x); v[1] = f2bf(a.y); v[2] = f2bf(a.z); v[3] = f2bf(a.w);
    v[4] = f2bf(b.x); v[5] = f2bf(b.y); v[6] = f2bf(b.z); v[7] = f2bf(b.w);
    reinterpret_cast<u16x8*>(Xb)[i] = v;
    return;
  }
  const float* in; u16* out; int R, C, bx, by;
  if (bid < 16384) {
    int b2 = bid - 4096;
    in = wat; out = Wa_t; R = 2048; C = 6144;
    bx = (b2 % 192) * 32; by = (b2 / 192) * 32;
  } else {
    int b3 = bid - 16384;
    in = wpr; out = Wp_t; R = 2048; C = 2048;
    bx = (b3 % 64) * 32; by = (b3 / 64) * 32;
  }
  int x = tid & 31, y = tid >> 5;  // (32, 8)
  #pragma unroll
  for (int k = 0; k < 32; k += 8)
    t[y + k][x] = in[(size_t)(by + y + k) * C + (bx + x)];
  __syncthreads();
  #pragma unroll
  for (int k = 0; k < 32; k += 8)
    out[(size_t)(bx + y + k) * R + (by + x)] = f2bf(t[x][y + k]);
}

// ------- V transpose from qkv: out[bh][d][s] = qkv[b][s][4096 + h*256 + d] ----------
__global__ void tv_kernel(const u16* __restrict__ qkv, u16* __restrict__ out) {
  __shared__ u16 t[32][33];
  int bh = blockIdx.z, b = bh >> 3, h = bh & 7;
  const u16* ip = qkv + (size_t)b * 2048 * 6144 + 4096 + h * 256;
  u16* op = out + (size_t)bh * 256 * 2048;
  int bx = blockIdx.x * 32, by = blockIdx.y * 32;  // bx: d, by: s
  int x = threadIdx.x, y = threadIdx.y;
  #pragma unroll
  for (int k = 0; k < 32; k += 8)
    t[y + k][x] = ip[(size_t)(by + y + k) * 6144 + (bx + x)];
  __syncthreads();
  #pragma unroll
  for (int k = 0; k < 32; k += 8)
    op[(size_t)(bx + y + k) * 2048 + (by + x)] = t[x][y + k];
}

// ------------- 2-blocks/CU pipelined GEMM: C = A[M,K] * Bt[N,K]^T (bf16 in) -------------
// Measured: 1033 TF, MfmaUtil 48%, 0 bank conflicts, FETCH ~93MB (qkv shape).
// 512 thr (8 waves WMxWN), BK=64, LDS 2 bufs of (BM+BN)*128 B; rows 128B,
// swizzle (row&7)<<4 both-sides involution. Per K-tile: s_barrier -> stage(t+1)
// -> vmcnt(NSTG) [tile t landed, t+1 in flight] -> s_barrier -> per-ks frags+MFMA.
// 2 blocks/CU so the co-resident block fills read/barrier stall windows (m114).
// No XCD swizzle: default x-major round-robin already L2-partitions the B-panel (r11).
template<int WM, int WN, int MF, int NF, bool F32OUT>
__global__ __launch_bounds__(512, 4) void gemm2b_kernel(
    const u16* __restrict__ A, const u16* __restrict__ Bt,
    float* __restrict__ Cf, u16* __restrict__ Cb, int M, int N, int K) {
  constexpr int BM = WM * MF * 16;
  constexpr int BN = WN * NF * 16;
  constexpr int TILEB = (BM + BN) * 128;
  constexpr int NSTG = TILEB / 8192;
  __shared__ __align__(16) char smem[2 * TILEB];

  const int tid = threadIdx.x, lane = tid & 63, w = tid >> 6;
  const int wr = w / WN, wc = w % WN;
  const int g = lane >> 4, li = lane & 15;
  const int bn = blockIdx.x * BN, bm = blockIdx.y * BM;

  const char* src[NSTG]; u32 dOff[NSTG];
  #pragma unroll
  for (int j = 0; j < NSTG; ++j) {
    int o = j * 8192 + tid * 16;
    if (o < BM * 128) {
      int row = o >> 7;
      int col = (o & 127) ^ ((row & 7) << 4);
      src[j] = (const char*)A + (size_t)(bm + row) * K * 2 + col;
    } else {
      int rem = o - BM * 128;
      int row = rem >> 7;
      int col = (rem & 127) ^ ((row & 7) << 4);
      src[j] = (const char*)Bt + (size_t)(bn + row) * K * 2 + col;
    }
    dOff[j] = (u32)(o - lane * 16);
  }

  u32 aRd[2][MF], bRd[2][NF];
  #pragma unroll
  for (int ks = 0; ks < 2; ++ks) {
    #pragma unroll
    for (int mf = 0; mf < MF; ++mf) {
      int row = wr * (MF * 16) + mf * 16 + li;
      aRd[ks][mf] = row * 128 + ((ks * 64 + g * 16) ^ ((row & 7) << 4));
    }
    #pragma unroll
    for (int nf = 0; nf < NF; ++nf) {
      int row = wc * (NF * 16) + nf * 16 + li;
      bRd[ks][nf] = BM * 128 + row * 128 + ((ks * 64 + g * 16) ^ ((row & 7) << 4));
    }
  }

  const f32x4 fz = {0.f, 0.f, 0.f, 0.f};
  f32x4 acc[MF][NF];
  #pragma unroll
  for (int i = 0; i < MF; ++i)
    #pragma unroll
    for (int j = 0; j < NF; ++j) acc[i][j] = fz;

  const int NT = K >> 6;
  #pragma unroll
  for (int j = 0; j < NSTG; ++j) { g2l16(src[j], smem + dOff[j]); src[j] += 128; }

  for (int t = 0; t < NT; ++t) {
    const int cur = t & 1;
    const bool more = (t + 1 < NT);
    asm volatile("s_barrier" ::: "memory");
    if (more) {
      char* nb = smem + (cur ^ 1) * TILEB;
      #pragma unroll
      for (int j = 0; j < NSTG; ++j) { g2l16(src[j], nb + dOff[j]); src[j] += 128; }
      asm volatile("s_waitcnt vmcnt(%0)" :: "i"(NSTG) : "memory");
    } else {
      asm volatile("s_waitcnt vmcnt(0)" ::: "memory");
    }
    asm volatile("s_barrier" ::: "memory");

    const char* sb = smem + cur * TILEB;
    #pragma unroll
    for (int ks = 0; ks < 2; ++ks) {
      bf16x8 aR[MF], bR[NF];
      #pragma unroll
      for (int mf = 0; mf < MF; ++mf) aR[mf] = ld8(sb + aRd[ks][mf]);
      #pragma unroll
      for (int nf = 0; nf < NF; ++nf) bR[nf] = ld8(sb + bRd[ks][nf]);
      __builtin_amdgcn_s_setprio(1);
      #pragma unroll
      for (int mf = 0; mf < MF; ++mf)
        #pragma unroll
        for (int nf = 0; nf < NF; ++nf)
          acc[mf][nf] = __builtin_amdgcn_mfma_f32_16x16x32_bf16(aR[mf], bR[nf], acc[mf][nf], 0, 0, 0);
      __builtin_amdgcn_s_setprio(0);
    }
  }

  #pragma unroll
  for (int mf = 0; mf < MF; ++mf)
    #pragma unroll
    for (int nf = 0; nf < NF; ++nf)
      #pragma unroll
      for (int r = 0; r < 4; ++r) {
        int gm = bm + wr * (MF * 16) + mf * 16 + g * 4 + r;
        int gn = bn + wc * (NF * 16) + nf * 16 + li;
        if (F32OUT) Cf[(size_t)gm * N + gn] = acc[mf][nf][r];
        else        Cb[(size_t)gm * N + gn] = f2bf(acc[mf][nf][r]);
      }
}

// ---------------- flash attention + fused PMSNorm (in-block split-k, balanced) ----------
// 256 blocks x 512 thr. Block c: bh=c&15, i=c>>4; units qt={i, 31-i} sequential
// (uniform 66 KV-tiles/block). Waves: kh=w>>2 (KV half), wq=w&3 (16 q-rows).
// Per half: K dbuf + V + P counted-vmcnt pipeline; halves run equal tile counts so
// block barriers align. Per-unit LDS merge (flash-decoding combine) + PMSNorm.
__global__ __launch_bounds__(512, 2) void attn_kernel(
    const u16* __restrict__ qkv, const u16* __restrict__ Vt,
    const float* __restrict__ nw, u16* __restrict__ Mrg) {
  __shared__ __align__(16) char smem[106496];       // 104 KiB
  char* sKb = smem;
  char* sVb = smem + 65536;
  char* sPb = smem + 65536 + 32768;
  float* oex  = (float*)smem;
  float* mlex = (float*)(smem + 65536);

  const int c = blockIdx.x;
  const int bh = c & 15, iu = c >> 4;
  const int b = bh >> 3, h = bh & 7;
  const int tid = threadIdx.x, lane = tid & 63, w = tid >> 6;
  const int kh = w >> 2, wq = w & 3;
  const int g = lane >> 4, li = lane & 15;
  const float MASKV = -30000.0f;
  const float MINIT = -1000.0f;
  const float isc = 1.0f / 64.0f; // 1 / (sqrt(256) * (LAYER_IDX+1))
  const f32x4 fz = {0.f, 0.f, 0.f, 0.f};
  const size_t KADV = (size_t)32 * 6144 * 2;

  #pragma unroll 1
  for (int uu = 0; uu < 2; ++uu) {
    const int qt = uu ? (31 - iu) : iu;
    const int nt = qt + 1;
    const int kvb0 = kh * nt * 32;

    int qrow = qt * 64 + wq * 16 + li;
    const u16* qp = qkv + (size_t)(b * 2048 + qrow) * 6144 + h * 256;
    bf16x8 qf[8];
    #pragma unroll
    for (int c8 = 0; c8 < 8; ++c8) qf[c8] = ld8(qp + c8 * 32 + g * 8);

    const char* kSrc[4]; u32 kDoff[4];
    #pragma unroll
    for (int j = 0; j < 4; ++j) {
      int chunk = wq * 4 + j;
      int o = chunk * 1024 + lane * 16;
      int row = o >> 9, cb = o & 511;
      int cbs = cb ^ ((row & 7) << 4);
      kSrc[j] = (const char*)qkv + ((size_t)(b * 2048 + kvb0 + row) * 6144 + 2048 + h * 256) * 2 + cbs;
      kDoff[j] = chunk * 1024;
    }
    const char* vSrc[4]; char* vDst[4];
    #pragma unroll
    for (int j = 0; j < 4; ++j) {
      int chunk = wq * 4 + j;
      int o = chunk * 1024 + lane * 16;
      int row = o >> 6, cb = o & 63;
      int cbs = cb ^ (((row >> 1) & 3) << 4);
      vSrc[j] = (const char*)Vt + ((size_t)(bh * 256 + row) * 2048 + kvb0) * 2 + cbs;
      vDst[j] = sVb + kh * 16384 + chunk * 1024;
    }

    f32x4 o_[16];
    #pragma unroll
    for (int nf = 0; nf < 16; ++nf) o_[nf] = fz;
    float m_[4] = {MINIT, MINIT, MINIT, MINIT};
    float l_[4] = {0.f, 0.f, 0.f, 0.f};

    {
      char* kb0 = sKb + (kh * 2 + 0) * 16384;
      #pragma unroll
      for (int j = 0; j < 4; ++j) { g2l16(kSrc[j], kb0 + kDoff[j]); kSrc[j] += KADV; }
    }
    asm volatile("s_waitcnt vmcnt(0)" ::: "memory");
    asm volatile("s_barrier" ::: "memory");

    int cur = 0;
    for (int t = 0; t < nt; ++t) {
      const bool more = (t < nt - 1);
      #pragma unroll
      for (int j = 0; j < 4; ++j) { g2l16(vSrc[j], vDst[j]); vSrc[j] += 64; }
      if (more) {
        char* kb = sKb + (kh * 2 + (cur ^ 1)) * 16384;
        #pragma unroll
        for (int j = 0; j < 4; ++j) { g2l16(kSrc[j], kb + kDoff[j]); kSrc[j] += KADV; }
      }

      f32x4 sacc[2];
      const char* kbase = sKb + (kh * 2 + cur) * 16384;
      __builtin_amdgcn_s_setprio(1);
      #pragma unroll
      for (int nf = 0; nf < 2; ++nf) {
        int row = nf * 16 + li;
        int swz = (row & 7) << 4;
        const char* kr = kbase + row * 512;
        f32x4 sa = fz, sb = fz;
        #pragma unroll
        for (int c8 = 0; c8 < 4; ++c8) {
          sa = __builtin_amdgcn_mfma_f32_16x16x32_bf16(qf[c8],     ld8(kr + ((c8 * 64 + g * 16) ^ swz)),       sa, 0, 0, 0);
          sb = __builtin_amdgcn_mfma_f32_16x16x32_bf16(qf[c8 + 4], ld8(kr + (((c8 + 4) * 64 + g * 16) ^ swz)), sb, 0, 0, 0);
        }
        sacc[nf] = sa + sb;
      }
      __builtin_amdgcn_s_setprio(0);

      const int tidx = kh * nt + t;
      const bool diag = (tidx >= 2 * qt);
      float p[2][4], m0[4];
      #pragma unroll
      for (int r = 0; r < 4; ++r) {
        int qr = qt * 64 + wq * 16 + g * 4 + r;
        float a0 = sacc[0][r] * isc;
        float a1 = sacc[1][r] * isc;
        if (diag) {
          if (tidx * 32 + li > qr) a0 = MASKV;
          if (tidx * 32 + 16 + li > qr) a1 = MASKV;
        }
        p[0][r] = a0; p[1][r] = a1;
        m0[r] = fmaxf(a0, a1);
      }
      bool need = (m0[0] > m_[0] + 8.f) || (m0[1] > m_[1] + 8.f) ||
                  (m0[2] > m_[2] + 8.f) || (m0[3] > m_[3] + 8.f);
      if (__any(need)) {
        #pragma unroll
        for (int r = 0; r < 4; ++r) {
          float mx = m0[r];
          mx = fmaxf(mx, __shfl_xor(mx, 1));
          mx = fmaxf(mx, __shfl_xor(mx, 2));
          mx = fmaxf(mx, __shfl_xor(mx, 4));
          mx = fmaxf(mx, __shfl_xor(mx, 8));
          float mn = fmaxf(m_[r], mx);
          float sc = __expf(m_[r] - mn);
          l_[r] *= sc; m_[r] = mn;
          #pragma unroll
          for (int nf = 0; nf < 16; ++nf) o_[nf][r] *= sc;
        }
      }
      #pragma unroll
      for (int r = 0; r < 4; ++r) {
        float e0 = __expf(p[0][r] - m_[r]);
        float e1 = __expf(p[1][r] - m_[r]);
        p[0][r] = e0; p[1][r] = e1;
        l_[r] += e0 + e1;
      }

      if (more) asm volatile("s_waitcnt vmcnt(4)" ::: "memory");
      else      asm volatile("s_waitcnt vmcnt(0)" ::: "memory");
      asm volatile("s_barrier" ::: "memory");

      char* sPw = sPb + kh * 4096 + wq * 1024;
      #pragma unroll
      for (int r = 0; r < 4; ++r) {
        int row = g * 4 + r;
        int swz = ((row >> 1) & 3) << 4;
        #pragma unroll
        for (int nf = 0; nf < 2; ++nf)
          *(u16*)(sPw + row * 64 + (((nf * 16 + li) * 2) ^ swz)) = f2bf(p[nf][r]);
      }
      asm volatile("s_waitcnt lgkmcnt(0)" ::: "memory");
      __builtin_amdgcn_sched_barrier(0);

      __builtin_amdgcn_s_setprio(1);
      {
        const char* vb = sVb + kh * 16384;
        bf16x8 pa = ld8(sPw + li * 64 + ((g * 16) ^ (((li >> 1) & 3) << 4)));
        #pragma unroll
        for (int nf = 0; nf < 16; ++nf) {
          int row = nf * 16 + li;
          bf16x8 vf = ld8(vb + row * 64 + ((g * 16) ^ (((row >> 1) & 3) << 4)));
          o_[nf] = __builtin_amdgcn_mfma_f32_16x16x32_bf16(pa, vf, o_[nf], 0, 0, 0);
        }
      }
      __builtin_amdgcn_s_setprio(0);

      asm volatile("s_barrier" ::: "memory");
      if (more) asm volatile("s_waitcnt vmcnt(0)" ::: "memory");
      cur ^= 1;
    }

    if (kh == 1) {
      #pragma unroll
      for (int nf = 0; nf < 16; ++nf)
        *(f32x4*)(oex + wq * 4096 + nf * 256 + lane * 4) = o_[nf];
      #pragma unroll
      for (int r = 0; r < 4; ++r) {
        mlex[wq * 512 + r * 64 + lane] = l_[r];
        mlex[wq * 512 + 256 + r * 64 + lane] = m_[r];
      }
    }
    __syncthreads();
    if (kh == 0) {
      float aw[4], bw[4], inv_l[4];
      #pragma unroll
      for (int r = 0; r < 4; ++r) {
        float mB = mlex[wq * 512 + 256 + r * 64 + lane];
        float lB = mlex[wq * 512 + r * 64 + lane];
        float mm = fmaxf(m_[r], mB);
        aw[r] = __expf(m_[r] - mm);
        bw[r] = __expf(mB - mm);
        float lr = l_[r] * aw[r] + lB * bw[r];
        lr += __shfl_xor(lr, 1);
        lr += __shfl_xor(lr, 2);
        lr += __shfl_xor(lr, 4);
        lr += __shfl_xor(lr, 8);
        inv_l[r] = 1.0f / lr;
      }
      #pragma unroll
      for (int nf = 0; nf < 16; ++nf) {
        f32x4 ob = *(f32x4*)(oex + wq * 4096 + nf * 256 + lane * 4);
        #pragma unroll
        for (int r = 0; r < 4; ++r)
          o_[nf][r] = o_[nf][r] * aw[r] + ob[r] * bw[r];
      }
      #pragma unroll
      for (int r = 0; r < 4; ++r) {
        float ss = 0.f;
        #pragma unroll
        for (int nf = 0; nf < 16; ++nf) {
          float v = o_[nf][r] * inv_l[r];
          ss += v * v;
        }
        ss += __shfl_xor(ss, 1);
        ss += __shfl_xor(ss, 2);
        ss += __shfl_xor(ss, 4);
        ss += __shfl_xor(ss, 8);
        float rms = rsqrtf(ss * (1.0f / 256.0f) + 1e-5f);
        int row = qt * 64 + wq * 16 + g * 4 + r;
        #pragma unroll
        for (int nf = 0; nf < 16; ++nf) {
          int d = nf * 16 + li;
          float v = o_[nf][r] * inv_l[r] * rms * nw[d];
          Mrg[((size_t)(b * 2048 + row)) * 2048 + h * 256 + d] = f2bf(v);
        }
      }
    }
    __syncthreads();
  }
}

extern "C" void kernel_launch(void* const* d_in, const int* in_sizes, int n_in,
                              void* d_out, int out_size, void* d_ws, size_t ws_size,
                              hipStream_t stream) {
  const float* hs  = (const float*)d_in[0];   // [2,2048,2048]
  const float* wat = (const float*)d_in[1];   // [2048,6144]
  const float* wpr = (const float*)d_in[2];   // [2048,2048]
  const float* nw  = (const float*)d_in[3];   // [256]
  float* out = (float*)d_out;                 // [2,2048,2048] f32

  char* ws = (char*)d_ws;
  u16* Xb   = (u16*)(ws + 0);                    // 16 MiB  [4096][2048] bf16
  u16* Wp_t = (u16*)(ws + (16u << 20));          //  8 MiB  [2048][2048] bf16 (w_proj^T)
  u16* Qkv  = (u16*)(ws + (24u << 20));          // 48 MiB  [4096][6144] bf16
  u16* Vt   = (u16*)(ws + (72u << 20));          // 16 MiB  [16][256][2048] bf16
  u16* Mrg  = Xb;                                // aliases Xb (dead after GEMM1)
  u16* Wa_t = (u16*)d_out;                       // 24 MiB scratch (w_attn^T [6144][2048])

  dim3 t328(32, 8);
  prep_kernel<<<20480, 256, 0, stream>>>(hs, wat, wpr, Xb, Wa_t, Wp_t);
  // qkv: 128x192 tile -> grid 32x32 = 1024 blocks = 2 exact rounds at 2 blocks/CU
  gemm2b_kernel<2, 4, 4, 3, false><<<dim3(32, 32), 512, 0, stream>>>(
      Xb, Wa_t, nullptr, Qkv, 4096, 6144, 2048);
  tv_kernel<<<dim3(8, 64, 16), t328, 0, stream>>>(Qkv, Vt);
  attn_kernel<<<256, 512, 0, stream>>>(Qkv, Vt, nw, Mrg);
  // proj: 128x128 tile -> grid 16x32 = 512 blocks = 1 exact round at 2 blocks/CU
  gemm2b_kernel<2, 4, 4, 2, true><<<dim3(16, 32), 512, 0, stream>>>(
      Mrg, Wp_t, out, nullptr, 4096, 2048, 2048);
  (void)in_sizes; (void)n_in; (void)out_size; (void)ws_size;
}